// Round 12
// baseline (949.898 us; speedup 1.0000x reference)
//
#include <hip/hip_runtime.h>
#include <hip/hip_bf16.h>

typedef __attribute__((ext_vector_type(8))) short short8;
typedef __attribute__((ext_vector_type(4))) short short4v;
typedef __attribute__((ext_vector_type(4))) float float4v;

#define DEVI static __device__ __forceinline__

#if __has_builtin(__builtin_amdgcn_exp2f)
#define EXP2(x) __builtin_amdgcn_exp2f(x)
#else
#define EXP2(x) exp2f(x)
#endif

DEVI unsigned short f2bf(float f) {
  unsigned int u = __builtin_bit_cast(unsigned int, f);
  u += 0x7fffu + ((u >> 16) & 1u);
  return (unsigned short)(u >> 16);
}

// vendor-emitted packed f32->bf16 (v_cvt_pk_bf16_f32); NEVER hand-rolled asm (r5/r6 NaN)
DEVI short8 pack8(float4v a, float4v b) {  // elems 0..3 <- a, 4..7 <- b
  struct P4 { __hip_bfloat162 x, y, z, w; } t;
  t.x = __float22bfloat162_rn(make_float2(a[0], a[1]));
  t.y = __float22bfloat162_rn(make_float2(a[2], a[3]));
  t.z = __float22bfloat162_rn(make_float2(b[0], b[1]));
  t.w = __float22bfloat162_rn(make_float2(b[2], b[3]));
  short8 r;
  __builtin_memcpy(&r, &t, 16);
  return r;
}

DEVI short4v pack4(float a, float b, float c, float d) {
  struct P2 { __hip_bfloat162 x, y; } t;
  t.x = __float22bfloat162_rn(make_float2(a, b));
  t.y = __float22bfloat162_rn(make_float2(c, d));
  short4v r;
  __builtin_memcpy(&r, &t, 8);
  return r;
}

DEVI void gload16(const void* src, void* lds_dst) {
  __builtin_amdgcn_global_load_lds(
      (const __attribute__((address_space(1))) void*)src,
      (__attribute__((address_space(3))) void*)lds_dst, 16, 0, 0);
}

// C = A[M x K] * B[Nc x K]^T   (B row-major (out,in))
// AF32: A is f32 (convert to bf16 while staging) else bf16.
// CMODE: 0 = bf16 row-major C[M][Nc] (scaled by oscale);
//        1 = f32 row-major; 2 = bf16 TRANSPOSED CT[Nc][M].
template<int AF32, int CMODE>
__global__ __launch_bounds__(256, 2)
void gemm_bt128(const void* __restrict__ Ap, const float* __restrict__ Bp,
                void* __restrict__ Cp, int M, int Nc, int Kd, float oscale)
{
  __shared__ alignas(16) short As[128 * 40];
  __shared__ alignas(16) short Bs[128 * 40];

  const int tid = threadIdx.x;
  const int lane = tid & 63;
  const int wid = tid >> 6;
  const int rl = lane & 15;
  const int g = lane >> 4;
  const int bm = blockIdx.x * 128;
  const int bn = blockIdx.y * 128;
  const int wm = (wid >> 1) * 64;
  const int wn = (wid & 1) * 64;
  const int srow = tid >> 1;          // 0..127
  const int k0 = (tid & 1) * 16;      // 0 or 16

  float4v acc[4][4];
#pragma unroll
  for (int i = 0; i < 4; ++i)
#pragma unroll
    for (int j = 0; j < 4; ++j) acc[i][j] = (float4v)(0.0f);

  const float* Af = (const float*)Ap;
  const unsigned short* Ab = (const unsigned short*)Ap;

  float4v afr[4], bfr[4];
  short8 ah[2], bh[2];

  const int NK = Kd >> 5;

  auto loadA = [&](int ks) {
    size_t base = (size_t)(bm + srow) * Kd + ks * 32 + k0;
    if constexpr (AF32 != 0) {
      afr[0] = *(const float4v*)(Af + base);
      afr[1] = *(const float4v*)(Af + base + 4);
      afr[2] = *(const float4v*)(Af + base + 8);
      afr[3] = *(const float4v*)(Af + base + 12);
    } else {
      ah[0] = *(const short8*)(Ab + base);
      ah[1] = *(const short8*)(Ab + base + 8);
    }
  };
  auto loadB = [&](int ks) {
    size_t base = (size_t)(bn + srow) * Kd + ks * 32 + k0;
    bfr[0] = *(const float4v*)(Bp + base);
    bfr[1] = *(const float4v*)(Bp + base + 4);
    bfr[2] = *(const float4v*)(Bp + base + 8);
    bfr[3] = *(const float4v*)(Bp + base + 12);
  };

  loadA(0);
  loadB(0);

  for (int ks = 0; ks < NK; ++ks) {
    if constexpr (AF32 != 0) {
      ah[0] = pack8(afr[0], afr[1]);
      ah[1] = pack8(afr[2], afr[3]);
    }
    bh[0] = pack8(bfr[0], bfr[1]);
    bh[1] = pack8(bfr[2], bfr[3]);
    __syncthreads();  // all waves done reading LDS of previous tile
    *(short8*)(As + srow * 40 + k0)     = ah[0];
    *(short8*)(As + srow * 40 + k0 + 8) = ah[1];
    *(short8*)(Bs + srow * 40 + k0)     = bh[0];
    *(short8*)(Bs + srow * 40 + k0 + 8) = bh[1];
    __syncthreads();  // writes visible
    if (ks + 1 < NK) { loadA(ks + 1); loadB(ks + 1); }

    short8 a8[4], b8[4];
#pragma unroll
    for (int mt = 0; mt < 4; ++mt)
      a8[mt] = *(const short8*)(As + (wm + mt * 16 + rl) * 40 + 8 * g);
#pragma unroll
    for (int nt = 0; nt < 4; ++nt)
      b8[nt] = *(const short8*)(Bs + (wn + nt * 16 + rl) * 40 + 8 * g);
#pragma unroll
    for (int mt = 0; mt < 4; ++mt)
#pragma unroll
      for (int nt = 0; nt < 4; ++nt)
        acc[mt][nt] = __builtin_amdgcn_mfma_f32_16x16x32_bf16(a8[mt], b8[nt], acc[mt][nt], 0, 0, 0);
  }

#pragma unroll
  for (int mt = 0; mt < 4; ++mt)
#pragma unroll
    for (int nt = 0; nt < 4; ++nt) {
      const int col = bn + wn + nt * 16 + rl;
      const int row0 = bm + wm + mt * 16 + 4 * g;
      if constexpr (CMODE == 1) {
        float* C = (float*)Cp;
#pragma unroll
        for (int r = 0; r < 4; ++r)
          C[(size_t)(row0 + r) * Nc + col] = acc[mt][nt][r];
      } else if constexpr (CMODE == 0) {
        unsigned short* C = (unsigned short*)Cp;
#pragma unroll
        for (int r = 0; r < 4; ++r)
          C[(size_t)(row0 + r) * Nc + col] = f2bf(acc[mt][nt][r] * oscale);
      } else {  // CMODE==2: transposed bf16: CT[col][row], lane's 4 rows contiguous
        unsigned short* C = (unsigned short*)Cp;
        short4v w = pack4(acc[mt][nt][0], acc[mt][nt][1], acc[mt][nt][2], acc[mt][nt][3]);
        *(short4v*)(C + (size_t)col * M + row0) = w;
      }
    }
}

// Fused attention, softmax over the batch axis n (size 4).
// Grid: (L/128, H, 2) = (16,16,2) -> 512 blocks = 2 blocks/CU (64KB LDS each,
// launch_bounds caps VGPR for 4 waves/SIMD). Block z handles s-half z (32 tiles).
// 512 threads = 8 waves; wave w owns 16 l-rows, all 4 n.
// qb: bf16 [n*2048+l][1024], PRE-SCALED by log2(e)/8. kb: bf16 [n*2048+s][1024].
// vtb: bf16 TRANSPOSED [h*64+dk][n*2048+s].
// Output: f32 ATOMIC accumulation into outf[(n*2048+l)*1024 + h*64+dk]
// (s-sum splits cleanly across z; softmax is over n, per-s independent).
// LDS per buf (32KB): K: 4n x [32 s][128B], 16B chunk c holds global chunk c^(s&7).
//                     V^T: 4n x [64 dk][64B], 16B chunk c holds global chunk c^((dk>>1)&3).
// Double-buffered: stage t+1 issued at iter start, __syncthreads at end (drain is
// cheap: compute >> HBM latency); two independent blocks/CU overlap the barriers.
__global__ __launch_bounds__(512, 4)
void attn_bn(const unsigned short* __restrict__ qb,
             const unsigned short* __restrict__ kb,
             const unsigned short* __restrict__ vtb,
             float* __restrict__ outf)
{
  __shared__ alignas(128) char smem[65536];

  const int tid = threadIdx.x;
  const int lane = tid & 63;
  const int wid = tid >> 6;          // 0..7
  const int rl = lane & 15;
  const int g = lane >> 4;
  const int h = blockIdx.y;
  const int z = blockIdx.z;          // s-half
  const int l0 = blockIdx.x * 128 + wid * 16;

  // hoisted q B-fragments: qf[n][dh], lane holds q[l0+rl][h*64 + dh*32 + 8g + i]
  short8 qf[4][2];
#pragma unroll
  for (int n = 0; n < 4; ++n)
#pragma unroll
    for (int dh = 0; dh < 2; ++dh)
      qf[n][dh] = *(const short8*)(qb + (size_t)(n * 2048 + l0 + rl) * 1024 + h * 64 + dh * 32 + 8 * g);

  float4v ha[4][4];  // heads^T acc: ha[n][t] = dk rows 16t..16t+15, cols l
#pragma unroll
  for (int n = 0; n < 4; ++n)
#pragma unroll
    for (int t = 0; t < 4; ++t) ha[n][t] = (float4v)(0.0f);

  // staging: waves 0-3 stage K (n=wid), waves 4-7 stage V^T (n=wid-4). 4 gload16 each.
  // K swizzled: lane i -> row s=ii*8+(i>>3), global 16B chunk (i&7)^(i>>3).
  const size_t koff0 = ((size_t)(wid * 2048 + z * 1024) + (size_t)(lane >> 3)) * 1024
                     + (size_t)(h * 64) + (size_t)(((lane & 7) ^ (lane >> 3)) * 8);
  // V^T swizzled: lane i -> row dk=ii*16+(i>>2), global 16B chunk (i&3)^((i>>3)&3).
  const size_t voff0 = ((size_t)(h * 64) + (size_t)(lane >> 2)) * 8192
                     + (size_t)((wid - 4) * 2048 + z * 1024)
                     + (size_t)((((lane & 3) ^ ((lane >> 3) & 3)) * 8));

  auto stage = [&](int step, int b) {
    if (wid < 4) {
      char* kdst = smem + b * 32768 + wid * 4096;
      const unsigned short* ksrc = kb + koff0 + (size_t)step * 32 * 1024;
#pragma unroll
      for (int ii = 0; ii < 4; ++ii)
        gload16(ksrc + ii * 8192, kdst + ii * 1024);
    } else {
      char* vdst = smem + b * 32768 + 16384 + (wid - 4) * 4096;
      const unsigned short* vsrc = vtb + voff0 + (size_t)step * 32;
#pragma unroll
      for (int ii = 0; ii < 4; ++ii)
        gload16(vsrc + (size_t)ii * 16 * 8192, vdst + ii * 1024);
    }
  };

  stage(0, 0);
  __syncthreads();

  const unsigned xr = ((unsigned)((rl >> 1) & 3)) << 4;
  const unsigned half = ((unsigned)(g & 1)) << 3;

  for (int to = 0; to < 16; ++to) {
#pragma unroll
    for (int ti = 0; ti < 2; ++ti) {
      const int t = to * 2 + ti;
      char* kbase = smem + ti * 32768;   // compile-time buffer base
      char* vbase = kbase + 16384;

      if (t + 1 < 32) stage(t + 1, ti ^ 1);  // prefetch; lands during compute

      // scores^T = mfma(k, q): C[s][l], lane: s = ss*16 + 4g + r, l = l0 + rl.
      float4v sc[4][2];
#pragma unroll
      for (int n = 0; n < 4; ++n) {
        char* kn = kbase + n * 4096;
#pragma unroll
        for (int ss = 0; ss < 2; ++ss) {
          const int srw = ss * 16 + rl;
          const unsigned sw = ((unsigned)(srw & 7)) << 4;
          short8 kf0 = *(const short8*)(kn + srw * 128 + ((16u * (unsigned)g) ^ sw));
          short8 kf1 = *(const short8*)(kn + srw * 128 + ((64u + 16u * (unsigned)g) ^ sw));
          float4v c = (float4v)(0.0f);
          c = __builtin_amdgcn_mfma_f32_16x16x32_bf16(kf0, qf[n][0], c, 0, 0, 0);
          c = __builtin_amdgcn_mfma_f32_16x16x32_bf16(kf1, qf[n][1], c, 0, 0, 0);
          sc[n][ss] = c;
        }
      }

      // softmax over n=4 per ss-half, then PV for that half.
      // fmin bounds e <= 1.7e7, eps in sum bounds inv -> P in [0,1], NaN impossible.
#pragma unroll
      for (int ss = 0; ss < 2; ++ss) {
        float ex[4][4];  // [n][r]
#pragma unroll
        for (int n = 0; n < 4; ++n)
#pragma unroll
          for (int r = 0; r < 4; ++r)
            ex[n][r] = EXP2(fminf(sc[n][ss][r], 24.0f));
#pragma unroll
        for (int r = 0; r < 4; ++r) {
          float inv = __builtin_amdgcn_rcpf((ex[0][r] + ex[1][r]) + (ex[2][r] + ex[3][r]) + 1e-30f);
          ex[0][r] *= inv; ex[1][r] *= inv; ex[2][r] *= inv; ex[3][r] *= inv;
        }
        short4v pf[4];
#pragma unroll
        for (int n = 0; n < 4; ++n) {
          unsigned lo = (unsigned)f2bf(ex[n][0]) | ((unsigned)f2bf(ex[n][1]) << 16);
          unsigned hi = (unsigned)f2bf(ex[n][2]) | ((unsigned)f2bf(ex[n][3]) << 16);
          uint2 u; u.x = lo; u.y = hi;
          pf[n] = __builtin_bit_cast(short4v, u);
        }

        // PV half: heads^T[dk][l] += V^T[:, 16ss..16ss+16) * P^T half (16x16x16).
        // A slot (g,i) <- V^T[dk=16t4+rl][s=16ss+4g+i]; 8B block b=4ss+g of row dk
        // lives at chunk (b>>1)^((dk>>1)&3), half b&1.
        const unsigned chunk0 = 2u * (unsigned)ss + ((unsigned)g >> 1);
#pragma unroll
        for (int n = 0; n < 4; ++n) {
          char* vn = vbase + n * 4096;
#pragma unroll
          for (int t4 = 0; t4 < 4; ++t4) {
            const char* rowp = vn + (t4 * 16 + rl) * 64;
            short4v va = *(const short4v*)(rowp + (((chunk0 << 4) ^ xr) + half));
            ha[n][t4] = __builtin_amdgcn_mfma_f32_16x16x16bf16_1k(va, pf[n], ha[n][t4], 0, 0, 0);
          }
        }
      }

      __syncthreads();
    }
  }

  // epilogue: f32 atomic accumulation (s-halves from the two z-blocks sum here)
#pragma unroll
  for (int n = 0; n < 4; ++n)
#pragma unroll
    for (int tt = 0; tt < 4; ++tt) {
      size_t off = (size_t)(n * 2048 + l0 + rl) * 1024 + h * 64 + tt * 16 + 4 * g;
#pragma unroll
      for (int r = 0; r < 4; ++r)
        unsafeAtomicAdd(outf + off + r, ha[n][tt][r]);
    }
}

extern "C" void kernel_launch(void* const* d_in, const int* in_sizes, int n_in,
                              void* d_out, int out_size, void* d_ws, size_t ws_size,
                              hipStream_t stream)
{
  const float* Q  = (const float*)d_in[0];
  const float* K  = (const float*)d_in[1];
  const float* V  = (const float*)d_in[2];
  const float* Wq = (const float*)d_in[3];
  const float* Wo = (const float*)d_in[4];
  float* out = (float*)d_out;

  unsigned short* qb = (unsigned short*)d_ws;            // 16 MB each
  unsigned short* kw = qb + (size_t)8192 * 1024;
  unsigned short* vt = kw + (size_t)8192 * 1024;         // v^T [1024][8192]
  float* cbuf = (float*)d_ws;   // final GEMM C (f32, 32MB) -> overlays qb+kw, free after attn

  const float CS = 0.18033688011112042f;  // log2(e)/8: folds 1/sqrt(dk) + ln2 into q

  dim3 gg(64, 8), bb(256);
  // heads accumulator = d_out (f32): zero it, attn atomically accumulates into it.
  hipMemsetAsync(d_out, 0, (size_t)out_size * sizeof(float), stream);
  gemm_bt128<1, 0><<<gg, bb, 0, stream>>>(Q, Wq, qb, 8192, 1024, 1024, CS);
  gemm_bt128<1, 0><<<gg, bb, 0, stream>>>(K, Wq, kw, 8192, 1024, 1024, 1.0f);
  gemm_bt128<1, 2><<<gg, bb, 0, stream>>>(V, Wq, vt, 8192, 1024, 1024, 1.0f);
  attn_bn<<<dim3(16, 16, 2), dim3(512), 0, stream>>>(qb, kw, vt, (float*)d_out);
  // final projection: A = f32 heads (d_out), C -> cbuf (can't write d_out in place)
  gemm_bt128<1, 1><<<gg, bb, 0, stream>>>(d_out, Wo, cbuf, 8192, 1024, 1024, 1.0f);
  hipMemcpyAsync(d_out, cbuf, (size_t)out_size * sizeof(float),
                 hipMemcpyDeviceToDevice, stream);
}

// Round 13
// 851.961 us; speedup vs baseline: 1.1150x; 1.1150x over previous
//
#include <hip/hip_runtime.h>
#include <hip/hip_bf16.h>

typedef __attribute__((ext_vector_type(8))) short short8;
typedef __attribute__((ext_vector_type(4))) short short4v;
typedef __attribute__((ext_vector_type(4))) float float4v;

#define DEVI static __device__ __forceinline__

#if __has_builtin(__builtin_amdgcn_exp2f)
#define EXP2(x) __builtin_amdgcn_exp2f(x)
#else
#define EXP2(x) exp2f(x)
#endif

DEVI unsigned short f2bf(float f) {
  unsigned int u = __builtin_bit_cast(unsigned int, f);
  u += 0x7fffu + ((u >> 16) & 1u);
  return (unsigned short)(u >> 16);
}

DEVI float ubf(short s) {  // bf16 (as short) -> f32
  return __builtin_bit_cast(float, ((unsigned)(unsigned short)s) << 16);
}

// vendor-emitted packed f32->bf16 (v_cvt_pk_bf16_f32); NEVER hand-rolled asm (r5/r6 NaN)
DEVI short8 pack8(float4v a, float4v b) {  // elems 0..3 <- a, 4..7 <- b
  struct P4 { __hip_bfloat162 x, y, z, w; } t;
  t.x = __float22bfloat162_rn(make_float2(a[0], a[1]));
  t.y = __float22bfloat162_rn(make_float2(a[2], a[3]));
  t.z = __float22bfloat162_rn(make_float2(b[0], b[1]));
  t.w = __float22bfloat162_rn(make_float2(b[2], b[3]));
  short8 r;
  __builtin_memcpy(&r, &t, 16);
  return r;
}

DEVI short4v pack4(float a, float b, float c, float d) {
  struct P2 { __hip_bfloat162 x, y; } t;
  t.x = __float22bfloat162_rn(make_float2(a, b));
  t.y = __float22bfloat162_rn(make_float2(c, d));
  short4v r;
  __builtin_memcpy(&r, &t, 8);
  return r;
}

DEVI void gload16(const void* src, void* lds_dst) {
  __builtin_amdgcn_global_load_lds(
      (const __attribute__((address_space(1))) void*)src,
      (__attribute__((address_space(3))) void*)lds_dst, 16, 0, 0);
}

// C = A[M x K] * B[Nc x K]^T   (B row-major (out,in))
// AMODE: 0 = A bf16; 1 = A f32 (convert while staging); 2 = A = f32 Ap + bf16 Ap2 (sum).
// CMODE: 0 = bf16 row-major C[M][Nc] (scaled by oscale);
//        1 = f32 row-major; 2 = bf16 TRANSPOSED CT[Nc][M].
template<int AMODE, int CMODE>
__global__ __launch_bounds__(256, 2)
void gemm_bt128(const void* __restrict__ Ap, const void* __restrict__ Ap2,
                const float* __restrict__ Bp,
                void* __restrict__ Cp, int M, int Nc, int Kd, float oscale)
{
  __shared__ alignas(16) short As[128 * 40];
  __shared__ alignas(16) short Bs[128 * 40];

  const int tid = threadIdx.x;
  const int lane = tid & 63;
  const int wid = tid >> 6;
  const int rl = lane & 15;
  const int g = lane >> 4;
  const int bm = blockIdx.x * 128;
  const int bn = blockIdx.y * 128;
  const int wm = (wid >> 1) * 64;
  const int wn = (wid & 1) * 64;
  const int srow = tid >> 1;          // 0..127
  const int k0 = (tid & 1) * 16;      // 0 or 16

  float4v acc[4][4];
#pragma unroll
  for (int i = 0; i < 4; ++i)
#pragma unroll
    for (int j = 0; j < 4; ++j) acc[i][j] = (float4v)(0.0f);

  const float* Af = (const float*)Ap;
  const unsigned short* Ab = (const unsigned short*)Ap;
  const unsigned short* Ab2 = (const unsigned short*)Ap2;

  float4v afr[4], bfr[4];
  short8 ah[2], bh[2], a2[2];

  const int NK = Kd >> 5;

  auto loadA = [&](int ks) {
    size_t base = (size_t)(bm + srow) * Kd + ks * 32 + k0;
    if constexpr (AMODE != 0) {
      afr[0] = *(const float4v*)(Af + base);
      afr[1] = *(const float4v*)(Af + base + 4);
      afr[2] = *(const float4v*)(Af + base + 8);
      afr[3] = *(const float4v*)(Af + base + 12);
      if constexpr (AMODE == 2) {
        a2[0] = *(const short8*)(Ab2 + base);
        a2[1] = *(const short8*)(Ab2 + base + 8);
      }
    } else {
      ah[0] = *(const short8*)(Ab + base);
      ah[1] = *(const short8*)(Ab + base + 8);
    }
  };
  auto loadB = [&](int ks) {
    size_t base = (size_t)(bn + srow) * Kd + ks * 32 + k0;
    bfr[0] = *(const float4v*)(Bp + base);
    bfr[1] = *(const float4v*)(Bp + base + 4);
    bfr[2] = *(const float4v*)(Bp + base + 8);
    bfr[3] = *(const float4v*)(Bp + base + 12);
  };

  loadA(0);
  loadB(0);

  for (int ks = 0; ks < NK; ++ks) {
    if constexpr (AMODE == 2) {
      float4v s0 = afr[0], s1 = afr[1], s2 = afr[2], s3 = afr[3];
#pragma unroll
      for (int j = 0; j < 4; ++j) {
        s0[j] += ubf(a2[0][j]);
        s1[j] += ubf(a2[0][4 + j]);
        s2[j] += ubf(a2[1][j]);
        s3[j] += ubf(a2[1][4 + j]);
      }
      ah[0] = pack8(s0, s1);
      ah[1] = pack8(s2, s3);
    } else if constexpr (AMODE == 1) {
      ah[0] = pack8(afr[0], afr[1]);
      ah[1] = pack8(afr[2], afr[3]);
    }
    bh[0] = pack8(bfr[0], bfr[1]);
    bh[1] = pack8(bfr[2], bfr[3]);
    __syncthreads();  // all waves done reading LDS of previous tile
    *(short8*)(As + srow * 40 + k0)     = ah[0];
    *(short8*)(As + srow * 40 + k0 + 8) = ah[1];
    *(short8*)(Bs + srow * 40 + k0)     = bh[0];
    *(short8*)(Bs + srow * 40 + k0 + 8) = bh[1];
    __syncthreads();  // writes visible
    if (ks + 1 < NK) { loadA(ks + 1); loadB(ks + 1); }

    short8 a8[4], b8[4];
#pragma unroll
    for (int mt = 0; mt < 4; ++mt)
      a8[mt] = *(const short8*)(As + (wm + mt * 16 + rl) * 40 + 8 * g);
#pragma unroll
    for (int nt = 0; nt < 4; ++nt)
      b8[nt] = *(const short8*)(Bs + (wn + nt * 16 + rl) * 40 + 8 * g);
#pragma unroll
    for (int mt = 0; mt < 4; ++mt)
#pragma unroll
      for (int nt = 0; nt < 4; ++nt)
        acc[mt][nt] = __builtin_amdgcn_mfma_f32_16x16x32_bf16(a8[mt], b8[nt], acc[mt][nt], 0, 0, 0);
  }

#pragma unroll
  for (int mt = 0; mt < 4; ++mt)
#pragma unroll
    for (int nt = 0; nt < 4; ++nt) {
      const int col = bn + wn + nt * 16 + rl;
      const int row0 = bm + wm + mt * 16 + 4 * g;
      if constexpr (CMODE == 1) {
        float* C = (float*)Cp;
#pragma unroll
        for (int r = 0; r < 4; ++r)
          C[(size_t)(row0 + r) * Nc + col] = acc[mt][nt][r];
      } else if constexpr (CMODE == 0) {
        unsigned short* C = (unsigned short*)Cp;
#pragma unroll
        for (int r = 0; r < 4; ++r)
          C[(size_t)(row0 + r) * Nc + col] = f2bf(acc[mt][nt][r] * oscale);
      } else {  // CMODE==2: transposed bf16: CT[col][row], lane's 4 rows contiguous
        unsigned short* C = (unsigned short*)Cp;
        short4v w = pack4(acc[mt][nt][0], acc[mt][nt][1], acc[mt][nt][2], acc[mt][nt][3]);
        *(short4v*)(C + (size_t)col * M + row0) = w;
      }
    }
}

// Fused attention, softmax over the batch axis n (size 4).
// Grid: (L/128, H, 2) = (16,16,2) -> 512 blocks = 2 blocks/CU (64KB LDS, 16 waves/CU
// = 4 waves/SIMD): two independent barrier domains per CU hide each other's stalls.
// Block z handles s-half z (32 tiles). 512 threads = 8 waves; wave w owns 16 l-rows.
// qb: bf16 [n*2048+l][1024], PRE-SCALED by log2(e)/8. kb: bf16 [n*2048+s][1024].
// vtb: bf16 TRANSPOSED [h*64+dk][n*2048+s].
// Output (NO atomics): z=0 -> plain f32 stores into outf; z=1 -> bf16 stores into h1.
// The final GEMM sums the two partials while staging A.
// LDS per buf (32KB): K: 4n x [32 s][128B], 16B chunk c holds global chunk c^(s&7).
//                     V^T: 4n x [64 dk][64B], 16B chunk c holds global chunk c^((dk>>1)&3).
__global__ __launch_bounds__(512, 4)
void attn_bn(const unsigned short* __restrict__ qb,
             const unsigned short* __restrict__ kb,
             const unsigned short* __restrict__ vtb,
             float* __restrict__ outf,
             unsigned short* __restrict__ h1)
{
  __shared__ alignas(128) char smem[65536];

  const int tid = threadIdx.x;
  const int lane = tid & 63;
  const int wid = tid >> 6;          // 0..7
  const int rl = lane & 15;
  const int g = lane >> 4;
  const int h = blockIdx.y;
  const int z = blockIdx.z;          // s-half
  const int l0 = blockIdx.x * 128 + wid * 16;

  // hoisted q B-fragments: qf[n][dh], lane holds q[l0+rl][h*64 + dh*32 + 8g + i]
  short8 qf[4][2];
#pragma unroll
  for (int n = 0; n < 4; ++n)
#pragma unroll
    for (int dh = 0; dh < 2; ++dh)
      qf[n][dh] = *(const short8*)(qb + (size_t)(n * 2048 + l0 + rl) * 1024 + h * 64 + dh * 32 + 8 * g);

  float4v ha[4][4];  // heads^T acc: ha[n][t] = dk rows 16t..16t+15, cols l
#pragma unroll
  for (int n = 0; n < 4; ++n)
#pragma unroll
    for (int t = 0; t < 4; ++t) ha[n][t] = (float4v)(0.0f);

  // staging: waves 0-3 stage K (n=wid), waves 4-7 stage V^T (n=wid-4). 4 gload16 each.
  // K swizzled: lane i -> row s=ii*8+(i>>3), global 16B chunk (i&7)^(i>>3).
  const size_t koff0 = ((size_t)(wid * 2048 + z * 1024) + (size_t)(lane >> 3)) * 1024
                     + (size_t)(h * 64) + (size_t)(((lane & 7) ^ (lane >> 3)) * 8);
  // V^T swizzled: lane i -> row dk=ii*16+(i>>2), global 16B chunk (i&3)^((i>>3)&3).
  const size_t voff0 = ((size_t)(h * 64) + (size_t)(lane >> 2)) * 8192
                     + (size_t)((wid - 4) * 2048 + z * 1024)
                     + (size_t)((((lane & 3) ^ ((lane >> 3) & 3)) * 8));

  auto stage = [&](int step, int b) {
    if (wid < 4) {
      char* kdst = smem + b * 32768 + wid * 4096;
      const unsigned short* ksrc = kb + koff0 + (size_t)step * 32 * 1024;
#pragma unroll
      for (int ii = 0; ii < 4; ++ii)
        gload16(ksrc + ii * 8192, kdst + ii * 1024);
    } else {
      char* vdst = smem + b * 32768 + 16384 + (wid - 4) * 4096;
      const unsigned short* vsrc = vtb + voff0 + (size_t)step * 32;
#pragma unroll
      for (int ii = 0; ii < 4; ++ii)
        gload16(vsrc + (size_t)ii * 16 * 8192, vdst + ii * 1024);
    }
  };

  stage(0, 0);
  __syncthreads();

  const unsigned xr = ((unsigned)((rl >> 1) & 3)) << 4;
  const unsigned half = ((unsigned)(g & 1)) << 3;

  for (int to = 0; to < 16; ++to) {
#pragma unroll
    for (int ti = 0; ti < 2; ++ti) {
      const int t = to * 2 + ti;
      char* kbase = smem + ti * 32768;   // compile-time buffer base
      char* vbase = kbase + 16384;

      if (t + 1 < 32) stage(t + 1, ti ^ 1);  // prefetch; lands during compute

      // scores^T = mfma(k, q): C[s][l], lane: s = ss*16 + 4g + r, l = l0 + rl.
      float4v sc[4][2];
#pragma unroll
      for (int n = 0; n < 4; ++n) {
        char* kn = kbase + n * 4096;
#pragma unroll
        for (int ss = 0; ss < 2; ++ss) {
          const int srw = ss * 16 + rl;
          const unsigned sw = ((unsigned)(srw & 7)) << 4;
          short8 kf0 = *(const short8*)(kn + srw * 128 + ((16u * (unsigned)g) ^ sw));
          short8 kf1 = *(const short8*)(kn + srw * 128 + ((64u + 16u * (unsigned)g) ^ sw));
          float4v c = (float4v)(0.0f);
          c = __builtin_amdgcn_mfma_f32_16x16x32_bf16(kf0, qf[n][0], c, 0, 0, 0);
          c = __builtin_amdgcn_mfma_f32_16x16x32_bf16(kf1, qf[n][1], c, 0, 0, 0);
          sc[n][ss] = c;
        }
      }

      // softmax over n=4 per ss-half, then PV for that half.
      // fmin bounds e <= 1.7e7, eps in sum bounds inv -> P in [0,1], NaN impossible.
#pragma unroll
      for (int ss = 0; ss < 2; ++ss) {
        float ex[4][4];  // [n][r]
#pragma unroll
        for (int n = 0; n < 4; ++n)
#pragma unroll
          for (int r = 0; r < 4; ++r)
            ex[n][r] = EXP2(fminf(sc[n][ss][r], 24.0f));
#pragma unroll
        for (int r = 0; r < 4; ++r) {
          float inv = __builtin_amdgcn_rcpf((ex[0][r] + ex[1][r]) + (ex[2][r] + ex[3][r]) + 1e-30f);
          ex[0][r] *= inv; ex[1][r] *= inv; ex[2][r] *= inv; ex[3][r] *= inv;
        }
        short4v pf[4];
#pragma unroll
        for (int n = 0; n < 4; ++n) {
          unsigned lo = (unsigned)f2bf(ex[n][0]) | ((unsigned)f2bf(ex[n][1]) << 16);
          unsigned hi = (unsigned)f2bf(ex[n][2]) | ((unsigned)f2bf(ex[n][3]) << 16);
          uint2 u; u.x = lo; u.y = hi;
          pf[n] = __builtin_bit_cast(short4v, u);
        }

        // PV half: heads^T[dk][l] += V^T[:, 16ss..16ss+16) * P^T half (16x16x16).
        // A slot (g,i) <- V^T[dk=16t4+rl][s=16ss+4g+i]; 8B block b=4ss+g of row dk
        // lives at chunk (b>>1)^((dk>>1)&3), half b&1.
        const unsigned chunk0 = 2u * (unsigned)ss + ((unsigned)g >> 1);
#pragma unroll
        for (int n = 0; n < 4; ++n) {
          char* vn = vbase + n * 4096;
#pragma unroll
          for (int t4 = 0; t4 < 4; ++t4) {
            const char* rowp = vn + (t4 * 16 + rl) * 64;
            short4v va = *(const short4v*)(rowp + (((chunk0 << 4) ^ xr) + half));
            ha[n][t4] = __builtin_amdgcn_mfma_f32_16x16x16bf16_1k(va, pf[n], ha[n][t4], 0, 0, 0);
          }
        }
      }

      __syncthreads();
    }
  }

  // epilogue: partial heads^T -> z==0: f32 16B stores; z==1: bf16 8B stores.
  if (z == 0) {
#pragma unroll
    for (int n = 0; n < 4; ++n)
#pragma unroll
      for (int tt = 0; tt < 4; ++tt) {
        size_t off = (size_t)(n * 2048 + l0 + rl) * 1024 + h * 64 + tt * 16 + 4 * g;
        *(float4v*)(outf + off) = ha[n][tt];
      }
  } else {
#pragma unroll
    for (int n = 0; n < 4; ++n)
#pragma unroll
      for (int tt = 0; tt < 4; ++tt) {
        unsigned w0 = (unsigned)f2bf(ha[n][tt][0]) | ((unsigned)f2bf(ha[n][tt][1]) << 16);
        unsigned w1 = (unsigned)f2bf(ha[n][tt][2]) | ((unsigned)f2bf(ha[n][tt][3]) << 16);
        size_t off = (size_t)(n * 2048 + l0 + rl) * 1024 + h * 64 + tt * 16 + 4 * g;
        uint2 val; val.x = w0; val.y = w1;
        *(uint2*)(h1 + off) = val;
      }
  }
}

extern "C" void kernel_launch(void* const* d_in, const int* in_sizes, int n_in,
                              void* d_out, int out_size, void* d_ws, size_t ws_size,
                              hipStream_t stream)
{
  const float* Q  = (const float*)d_in[0];
  const float* K  = (const float*)d_in[1];
  const float* V  = (const float*)d_in[2];
  const float* Wq = (const float*)d_in[3];
  const float* Wo = (const float*)d_in[4];

  unsigned short* qb = (unsigned short*)d_ws;            // 16 MB each
  unsigned short* kw = qb + (size_t)8192 * 1024;
  unsigned short* vt = kw + (size_t)8192 * 1024;         // v^T [1024][8192]
  unsigned short* h1 = vt + (size_t)8192 * 1024;         // heads partial (s-half 1), bf16
  float* cbuf = (float*)d_ws;   // final GEMM C (f32, 32MB) overlays qb+kw (dead after attn)

  const float CS = 0.18033688011112042f;  // log2(e)/8: folds 1/sqrt(dk) + ln2 into q

  dim3 gg(64, 8), bb(256);
  gemm_bt128<1, 0><<<gg, bb, 0, stream>>>(Q, nullptr, Wq, qb, 8192, 1024, 1024, CS);
  gemm_bt128<1, 0><<<gg, bb, 0, stream>>>(K, nullptr, Wq, kw, 8192, 1024, 1024, 1.0f);
  gemm_bt128<1, 2><<<gg, bb, 0, stream>>>(V, nullptr, Wq, vt, 8192, 1024, 1024, 1.0f);
  // z=0 partial -> d_out (plain f32 stores); z=1 partial -> h1 (bf16)
  attn_bn<<<dim3(16, 16, 2), dim3(512), 0, stream>>>(qb, kw, vt, (float*)d_out, h1);
  // final projection: A = d_out(f32) + h1(bf16), C -> cbuf
  gemm_bt128<2, 1><<<gg, bb, 0, stream>>>(d_out, h1, Wo, cbuf, 8192, 1024, 1024, 1.0f);
  hipMemcpyAsync(d_out, cbuf, (size_t)out_size * sizeof(float),
                 hipMemcpyDeviceToDevice, stream);
}

// Round 14
// 313.233 us; speedup vs baseline: 3.0326x; 2.7199x over previous
//
#include <hip/hip_runtime.h>
#include <hip/hip_bf16.h>

typedef __attribute__((ext_vector_type(8))) short short8;
typedef __attribute__((ext_vector_type(4))) short short4v;
typedef __attribute__((ext_vector_type(4))) float float4v;

#define DEVI static __device__ __forceinline__

#if __has_builtin(__builtin_amdgcn_exp2f)
#define EXP2(x) __builtin_amdgcn_exp2f(x)
#else
#define EXP2(x) exp2f(x)
#endif

DEVI unsigned short f2bf(float f) {
  unsigned int u = __builtin_bit_cast(unsigned int, f);
  u += 0x7fffu + ((u >> 16) & 1u);
  return (unsigned short)(u >> 16);
}

DEVI float ubf(short s) {  // bf16 (as short) -> f32
  return __builtin_bit_cast(float, ((unsigned)(unsigned short)s) << 16);
}

// vendor-emitted packed f32->bf16 (v_cvt_pk_bf16_f32); NEVER hand-rolled asm (r5/r6 NaN)
DEVI short8 pack8(float4v a, float4v b) {  // elems 0..3 <- a, 4..7 <- b
  struct P4 { __hip_bfloat162 x, y, z, w; } t;
  t.x = __float22bfloat162_rn(make_float2(a[0], a[1]));
  t.y = __float22bfloat162_rn(make_float2(a[2], a[3]));
  t.z = __float22bfloat162_rn(make_float2(b[0], b[1]));
  t.w = __float22bfloat162_rn(make_float2(b[2], b[3]));
  short8 r;
  __builtin_memcpy(&r, &t, 16);
  return r;
}

DEVI short4v pack4(float a, float b, float c, float d) {
  struct P2 { __hip_bfloat162 x, y; } t;
  t.x = __float22bfloat162_rn(make_float2(a, b));
  t.y = __float22bfloat162_rn(make_float2(c, d));
  short4v r;
  __builtin_memcpy(&r, &t, 8);
  return r;
}

DEVI void gload16(const void* src, void* lds_dst) {
  __builtin_amdgcn_global_load_lds(
      (const __attribute__((address_space(1))) void*)src,
      (__attribute__((address_space(3))) void*)lds_dst, 16, 0, 0);
}

// C = A[M x K] * B[Nc x K]^T   (B row-major (out,in))
// AMODE: 0 = A bf16; 1 = A f32 (convert while staging); 2 = A = f32 Ap + bf16 Ap2 (sum).
// CMODE: 0 = bf16 row-major C[M][Nc] (scaled by oscale);
//        1 = f32 row-major; 2 = bf16 TRANSPOSED CT[Nc][M].
template<int AMODE, int CMODE>
__global__ __launch_bounds__(256, 2)
void gemm_bt128(const void* __restrict__ Ap, const void* __restrict__ Ap2,
                const float* __restrict__ Bp,
                void* __restrict__ Cp, int M, int Nc, int Kd, float oscale)
{
  __shared__ alignas(16) short As[128 * 40];
  __shared__ alignas(16) short Bs[128 * 40];

  const int tid = threadIdx.x;
  const int lane = tid & 63;
  const int wid = tid >> 6;
  const int rl = lane & 15;
  const int g = lane >> 4;
  const int bm = blockIdx.x * 128;
  const int bn = blockIdx.y * 128;
  const int wm = (wid >> 1) * 64;
  const int wn = (wid & 1) * 64;
  const int srow = tid >> 1;          // 0..127
  const int k0 = (tid & 1) * 16;      // 0 or 16

  float4v acc[4][4];
#pragma unroll
  for (int i = 0; i < 4; ++i)
#pragma unroll
    for (int j = 0; j < 4; ++j) acc[i][j] = (float4v)(0.0f);

  const float* Af = (const float*)Ap;
  const unsigned short* Ab = (const unsigned short*)Ap;
  const unsigned short* Ab2 = (const unsigned short*)Ap2;

  float4v afr[4], bfr[4];
  short8 ah[2], bh[2], a2[2];

  const int NK = Kd >> 5;

  auto loadA = [&](int ks) {
    size_t base = (size_t)(bm + srow) * Kd + ks * 32 + k0;
    if constexpr (AMODE != 0) {
      afr[0] = *(const float4v*)(Af + base);
      afr[1] = *(const float4v*)(Af + base + 4);
      afr[2] = *(const float4v*)(Af + base + 8);
      afr[3] = *(const float4v*)(Af + base + 12);
      if constexpr (AMODE == 2) {
        a2[0] = *(const short8*)(Ab2 + base);
        a2[1] = *(const short8*)(Ab2 + base + 8);
      }
    } else {
      ah[0] = *(const short8*)(Ab + base);
      ah[1] = *(const short8*)(Ab + base + 8);
    }
  };
  auto loadB = [&](int ks) {
    size_t base = (size_t)(bn + srow) * Kd + ks * 32 + k0;
    bfr[0] = *(const float4v*)(Bp + base);
    bfr[1] = *(const float4v*)(Bp + base + 4);
    bfr[2] = *(const float4v*)(Bp + base + 8);
    bfr[3] = *(const float4v*)(Bp + base + 12);
  };

  loadA(0);
  loadB(0);

  for (int ks = 0; ks < NK; ++ks) {
    if constexpr (AMODE == 2) {
      float4v s0 = afr[0], s1 = afr[1], s2 = afr[2], s3 = afr[3];
#pragma unroll
      for (int j = 0; j < 4; ++j) {
        s0[j] += ubf(a2[0][j]);
        s1[j] += ubf(a2[0][4 + j]);
        s2[j] += ubf(a2[1][j]);
        s3[j] += ubf(a2[1][4 + j]);
      }
      ah[0] = pack8(s0, s1);
      ah[1] = pack8(s2, s3);
    } else if constexpr (AMODE == 1) {
      ah[0] = pack8(afr[0], afr[1]);
      ah[1] = pack8(afr[2], afr[3]);
    }
    bh[0] = pack8(bfr[0], bfr[1]);
    bh[1] = pack8(bfr[2], bfr[3]);
    __syncthreads();  // all waves done reading LDS of previous tile
    *(short8*)(As + srow * 40 + k0)     = ah[0];
    *(short8*)(As + srow * 40 + k0 + 8) = ah[1];
    *(short8*)(Bs + srow * 40 + k0)     = bh[0];
    *(short8*)(Bs + srow * 40 + k0 + 8) = bh[1];
    __syncthreads();  // writes visible
    if (ks + 1 < NK) { loadA(ks + 1); loadB(ks + 1); }

    short8 a8[4], b8[4];
#pragma unroll
    for (int mt = 0; mt < 4; ++mt)
      a8[mt] = *(const short8*)(As + (wm + mt * 16 + rl) * 40 + 8 * g);
#pragma unroll
    for (int nt = 0; nt < 4; ++nt)
      b8[nt] = *(const short8*)(Bs + (wn + nt * 16 + rl) * 40 + 8 * g);
#pragma unroll
    for (int mt = 0; mt < 4; ++mt)
#pragma unroll
      for (int nt = 0; nt < 4; ++nt)
        acc[mt][nt] = __builtin_amdgcn_mfma_f32_16x16x32_bf16(a8[mt], b8[nt], acc[mt][nt], 0, 0, 0);
  }

#pragma unroll
  for (int mt = 0; mt < 4; ++mt)
#pragma unroll
    for (int nt = 0; nt < 4; ++nt) {
      const int col = bn + wn + nt * 16 + rl;
      const int row0 = bm + wm + mt * 16 + 4 * g;
      if constexpr (CMODE == 1) {
        float* C = (float*)Cp;
#pragma unroll
        for (int r = 0; r < 4; ++r)
          C[(size_t)(row0 + r) * Nc + col] = acc[mt][nt][r];
      } else if constexpr (CMODE == 0) {
        unsigned short* C = (unsigned short*)Cp;
#pragma unroll
        for (int r = 0; r < 4; ++r)
          C[(size_t)(row0 + r) * Nc + col] = f2bf(acc[mt][nt][r] * oscale);
      } else {  // CMODE==2: transposed bf16: CT[col][row], lane's 4 rows contiguous
        unsigned short* C = (unsigned short*)Cp;
        short4v w = pack4(acc[mt][nt][0], acc[mt][nt][1], acc[mt][nt][2], acc[mt][nt][3]);
        *(short4v*)(C + (size_t)col * M + row0) = w;
      }
    }
}

// Fused attention, softmax over the batch axis n (size 4).
// Grid: (L/128, H, 2) = (16,16,2) -> 512 blocks = 2 blocks/CU (64KB LDS each).
// launch_bounds(512, 2): allocator free to ~104 VGPR (<=128 -> 16 waves/CU still
// possible). r12/r13 used (512,4) which capped VGPR at 64 -> ~40 regs/thread
// SPILLED to scratch = ~1.1 GB each way of HBM traffic (the real 660us cause).
// Block z handles s-half z (32 tiles). 512 threads = 8 waves; wave w owns 16 l-rows.
// qb: bf16 [n*2048+l][1024], PRE-SCALED by log2(e)/8. kb: bf16 [n*2048+s][1024].
// vtb: bf16 TRANSPOSED [h*64+dk][n*2048+s].
// Output (NO atomics): z=0 -> plain f32 stores into outf; z=1 -> bf16 stores into h1.
// The final GEMM sums the two partials while staging A.
// LDS per buf (32KB): K: 4n x [32 s][128B], 16B chunk c holds global chunk c^(s&7).
//                     V^T: 4n x [64 dk][64B], 16B chunk c holds global chunk c^((dk>>1)&3).
__global__ __launch_bounds__(512, 2)
void attn_bn(const unsigned short* __restrict__ qb,
             const unsigned short* __restrict__ kb,
             const unsigned short* __restrict__ vtb,
             float* __restrict__ outf,
             unsigned short* __restrict__ h1)
{
  __shared__ alignas(128) char smem[65536];

  const int tid = threadIdx.x;
  const int lane = tid & 63;
  const int wid = tid >> 6;          // 0..7
  const int rl = lane & 15;
  const int g = lane >> 4;
  const int h = blockIdx.y;
  const int z = blockIdx.z;          // s-half
  const int l0 = blockIdx.x * 128 + wid * 16;

  // hoisted q B-fragments: qf[n][dh], lane holds q[l0+rl][h*64 + dh*32 + 8g + i]
  short8 qf[4][2];
#pragma unroll
  for (int n = 0; n < 4; ++n)
#pragma unroll
    for (int dh = 0; dh < 2; ++dh)
      qf[n][dh] = *(const short8*)(qb + (size_t)(n * 2048 + l0 + rl) * 1024 + h * 64 + dh * 32 + 8 * g);

  float4v ha[4][4];  // heads^T acc: ha[n][t] = dk rows 16t..16t+15, cols l
#pragma unroll
  for (int n = 0; n < 4; ++n)
#pragma unroll
    for (int t = 0; t < 4; ++t) ha[n][t] = (float4v)(0.0f);

  // staging: waves 0-3 stage K (n=wid), waves 4-7 stage V^T (n=wid-4). 4 gload16 each.
  // K swizzled: lane i -> row s=ii*8+(i>>3), global 16B chunk (i&7)^(i>>3).
  const size_t koff0 = ((size_t)(wid * 2048 + z * 1024) + (size_t)(lane >> 3)) * 1024
                     + (size_t)(h * 64) + (size_t)(((lane & 7) ^ (lane >> 3)) * 8);
  // V^T swizzled: lane i -> row dk=ii*16+(i>>2), global 16B chunk (i&3)^((i>>3)&3).
  const size_t voff0 = ((size_t)(h * 64) + (size_t)(lane >> 2)) * 8192
                     + (size_t)((wid - 4) * 2048 + z * 1024)
                     + (size_t)((((lane & 3) ^ ((lane >> 3) & 3)) * 8));

  auto stage = [&](int step, int b) {
    if (wid < 4) {
      char* kdst = smem + b * 32768 + wid * 4096;
      const unsigned short* ksrc = kb + koff0 + (size_t)step * 32 * 1024;
#pragma unroll
      for (int ii = 0; ii < 4; ++ii)
        gload16(ksrc + ii * 8192, kdst + ii * 1024);
    } else {
      char* vdst = smem + b * 32768 + 16384 + (wid - 4) * 4096;
      const unsigned short* vsrc = vtb + voff0 + (size_t)step * 32;
#pragma unroll
      for (int ii = 0; ii < 4; ++ii)
        gload16(vsrc + (size_t)ii * 16 * 8192, vdst + ii * 1024);
    }
  };

  stage(0, 0);
  __syncthreads();

  const unsigned xr = ((unsigned)((rl >> 1) & 3)) << 4;
  const unsigned half = ((unsigned)(g & 1)) << 3;

  for (int to = 0; to < 16; ++to) {
#pragma unroll
    for (int ti = 0; ti < 2; ++ti) {
      const int t = to * 2 + ti;
      char* kbase = smem + ti * 32768;   // compile-time buffer base
      char* vbase = kbase + 16384;

      if (t + 1 < 32) stage(t + 1, ti ^ 1);  // prefetch; lands during compute

      // scores^T = mfma(k, q): C[s][l], lane: s = ss*16 + 4g + r, l = l0 + rl.
      float4v sc[4][2];
#pragma unroll
      for (int n = 0; n < 4; ++n) {
        char* kn = kbase + n * 4096;
#pragma unroll
        for (int ss = 0; ss < 2; ++ss) {
          const int srw = ss * 16 + rl;
          const unsigned sw = ((unsigned)(srw & 7)) << 4;
          short8 kf0 = *(const short8*)(kn + srw * 128 + ((16u * (unsigned)g) ^ sw));
          short8 kf1 = *(const short8*)(kn + srw * 128 + ((64u + 16u * (unsigned)g) ^ sw));
          float4v c = (float4v)(0.0f);
          c = __builtin_amdgcn_mfma_f32_16x16x32_bf16(kf0, qf[n][0], c, 0, 0, 0);
          c = __builtin_amdgcn_mfma_f32_16x16x32_bf16(kf1, qf[n][1], c, 0, 0, 0);
          sc[n][ss] = c;
        }
      }

      // softmax over n=4 per ss-half, then PV for that half.
      // fmin bounds e <= 1.7e7, eps in sum bounds inv -> P in [0,1], NaN impossible.
#pragma unroll
      for (int ss = 0; ss < 2; ++ss) {
        float ex[4][4];  // [n][r]
#pragma unroll
        for (int n = 0; n < 4; ++n)
#pragma unroll
          for (int r = 0; r < 4; ++r)
            ex[n][r] = EXP2(fminf(sc[n][ss][r], 24.0f));
#pragma unroll
        for (int r = 0; r < 4; ++r) {
          float inv = __builtin_amdgcn_rcpf((ex[0][r] + ex[1][r]) + (ex[2][r] + ex[3][r]) + 1e-30f);
          ex[0][r] *= inv; ex[1][r] *= inv; ex[2][r] *= inv; ex[3][r] *= inv;
        }
        short4v pf[4];
#pragma unroll
        for (int n = 0; n < 4; ++n) {
          unsigned lo = (unsigned)f2bf(ex[n][0]) | ((unsigned)f2bf(ex[n][1]) << 16);
          unsigned hi = (unsigned)f2bf(ex[n][2]) | ((unsigned)f2bf(ex[n][3]) << 16);
          uint2 u; u.x = lo; u.y = hi;
          pf[n] = __builtin_bit_cast(short4v, u);
        }

        // PV half: heads^T[dk][l] += V^T[:, 16ss..16ss+16) * P^T half (16x16x16).
        // A slot (g,i) <- V^T[dk=16t4+rl][s=16ss+4g+i]; 8B block b=4ss+g of row dk
        // lives at chunk (b>>1)^((dk>>1)&3), half b&1.
        const unsigned chunk0 = 2u * (unsigned)ss + ((unsigned)g >> 1);
#pragma unroll
        for (int n = 0; n < 4; ++n) {
          char* vn = vbase + n * 4096;
#pragma unroll
          for (int t4 = 0; t4 < 4; ++t4) {
            const char* rowp = vn + (t4 * 16 + rl) * 64;
            short4v va = *(const short4v*)(rowp + (((chunk0 << 4) ^ xr) + half));
            ha[n][t4] = __builtin_amdgcn_mfma_f32_16x16x16bf16_1k(va, pf[n], ha[n][t4], 0, 0, 0);
          }
        }
      }

      __syncthreads();
    }
  }

  // epilogue: partial heads^T -> z==0: f32 16B stores; z==1: bf16 8B stores.
  if (z == 0) {
#pragma unroll
    for (int n = 0; n < 4; ++n)
#pragma unroll
      for (int tt = 0; tt < 4; ++tt) {
        size_t off = (size_t)(n * 2048 + l0 + rl) * 1024 + h * 64 + tt * 16 + 4 * g;
        *(float4v*)(outf + off) = ha[n][tt];
      }
  } else {
#pragma unroll
    for (int n = 0; n < 4; ++n)
#pragma unroll
      for (int tt = 0; tt < 4; ++tt) {
        unsigned w0 = (unsigned)f2bf(ha[n][tt][0]) | ((unsigned)f2bf(ha[n][tt][1]) << 16);
        unsigned w1 = (unsigned)f2bf(ha[n][tt][2]) | ((unsigned)f2bf(ha[n][tt][3]) << 16);
        size_t off = (size_t)(n * 2048 + l0 + rl) * 1024 + h * 64 + tt * 16 + 4 * g;
        uint2 val; val.x = w0; val.y = w1;
        *(uint2*)(h1 + off) = val;
      }
  }
}

extern "C" void kernel_launch(void* const* d_in, const int* in_sizes, int n_in,
                              void* d_out, int out_size, void* d_ws, size_t ws_size,
                              hipStream_t stream)
{
  const float* Q  = (const float*)d_in[0];
  const float* K  = (const float*)d_in[1];
  const float* V  = (const float*)d_in[2];
  const float* Wq = (const float*)d_in[3];
  const float* Wo = (const float*)d_in[4];

  unsigned short* qb = (unsigned short*)d_ws;            // 16 MB each
  unsigned short* kw = qb + (size_t)8192 * 1024;
  unsigned short* vt = kw + (size_t)8192 * 1024;         // v^T [1024][8192]
  unsigned short* h1 = vt + (size_t)8192 * 1024;         // heads partial (s-half 1), bf16
  float* cbuf = (float*)d_ws;   // final GEMM C (f32, 32MB) overlays qb+kw (dead after attn)

  const float CS = 0.18033688011112042f;  // log2(e)/8: folds 1/sqrt(dk) + ln2 into q

  dim3 gg(64, 8), bb(256);
  gemm_bt128<1, 0><<<gg, bb, 0, stream>>>(Q, nullptr, Wq, qb, 8192, 1024, 1024, CS);
  gemm_bt128<1, 0><<<gg, bb, 0, stream>>>(K, nullptr, Wq, kw, 8192, 1024, 1024, 1.0f);
  gemm_bt128<1, 2><<<gg, bb, 0, stream>>>(V, nullptr, Wq, vt, 8192, 1024, 1024, 1.0f);
  // z=0 partial -> d_out (plain f32 stores); z=1 partial -> h1 (bf16)
  attn_bn<<<dim3(16, 16, 2), dim3(512), 0, stream>>>(qb, kw, vt, (float*)d_out, h1);
  // final projection: A = d_out(f32) + h1(bf16), C -> cbuf
  gemm_bt128<2, 1><<<gg, bb, 0, stream>>>(d_out, h1, Wo, cbuf, 8192, 1024, 1024, 1.0f);
  hipMemcpyAsync(d_out, cbuf, (size_t)out_size * sizeof(float),
                 hipMemcpyDeviceToDevice, stream);
}

// Round 15
// 273.474 us; speedup vs baseline: 3.4734x; 1.1454x over previous
//
#include <hip/hip_runtime.h>
#include <hip/hip_bf16.h>

typedef __attribute__((ext_vector_type(8))) short short8;
typedef __attribute__((ext_vector_type(4))) short short4v;
typedef __attribute__((ext_vector_type(4))) float float4v;

#define DEVI static __device__ __forceinline__

#if __has_builtin(__builtin_amdgcn_exp2f)
#define EXP2(x) __builtin_amdgcn_exp2f(x)
#else
#define EXP2(x) exp2f(x)
#endif

DEVI unsigned short f2bf(float f) {
  unsigned int u = __builtin_bit_cast(unsigned int, f);
  u += 0x7fffu + ((u >> 16) & 1u);
  return (unsigned short)(u >> 16);
}

// vendor-emitted packed f32->bf16 (v_cvt_pk_bf16_f32); NEVER hand-rolled asm (r5/r6 NaN)
DEVI short8 pack8(float4v a, float4v b) {  // elems 0..3 <- a, 4..7 <- b
  struct P4 { __hip_bfloat162 x, y, z, w; } t;
  t.x = __float22bfloat162_rn(make_float2(a[0], a[1]));
  t.y = __float22bfloat162_rn(make_float2(a[2], a[3]));
  t.z = __float22bfloat162_rn(make_float2(b[0], b[1]));
  t.w = __float22bfloat162_rn(make_float2(b[2], b[3]));
  short8 r;
  __builtin_memcpy(&r, &t, 16);
  return r;
}

DEVI short4v pack4(float a, float b, float c, float d) {
  struct P2 { __hip_bfloat162 x, y; } t;
  t.x = __float22bfloat162_rn(make_float2(a, b));
  t.y = __float22bfloat162_rn(make_float2(c, d));
  short4v r;
  __builtin_memcpy(&r, &t, 8);
  return r;
}

DEVI void gload16(const void* src, void* lds_dst) {
  __builtin_amdgcn_global_load_lds(
      (const __attribute__((address_space(1))) void*)src,
      (__attribute__((address_space(3))) void*)lds_dst, 16, 0, 0);
}

// C = A[M x K] * B[Nc x K]^T   (B row-major (out,in))
// AF32: A is f32 (convert to bf16 while staging) else bf16.
// CMODE: 0 = bf16 row-major C[M][Nc] (scaled by oscale);
//        1 = f32 row-major; 2 = bf16 TRANSPOSED CT[Nc][M].
// LDS DOUBLE-BUFFERED: one __syncthreads per K-step (write buf^1 while reading buf;
// cross-buffer WAR is fenced by the previous iteration's barrier). The old
// single-buffer version paid two vmcnt(0)-draining barriers per K-step.
template<int AF32, int CMODE>
__global__ __launch_bounds__(256, 2)
void gemm_bt128(const void* __restrict__ Ap, const float* __restrict__ Bp,
                void* __restrict__ Cp, int M, int Nc, int Kd, float oscale)
{
  __shared__ alignas(16) short As[2][128 * 40];
  __shared__ alignas(16) short Bs[2][128 * 40];

  const int tid = threadIdx.x;
  const int lane = tid & 63;
  const int wid = tid >> 6;
  const int rl = lane & 15;
  const int g = lane >> 4;
  const int bm = blockIdx.x * 128;
  const int bn = blockIdx.y * 128;
  const int wm = (wid >> 1) * 64;
  const int wn = (wid & 1) * 64;
  const int srow = tid >> 1;          // 0..127
  const int k0 = (tid & 1) * 16;      // 0 or 16

  float4v acc[4][4];
#pragma unroll
  for (int i = 0; i < 4; ++i)
#pragma unroll
    for (int j = 0; j < 4; ++j) acc[i][j] = (float4v)(0.0f);

  const float* Af = (const float*)Ap;
  const unsigned short* Ab = (const unsigned short*)Ap;

  float4v afr[4], bfr[4];
  short8 ah[2], bh[2];

  const int NK = Kd >> 5;

  auto loadA = [&](int ks) {
    size_t base = (size_t)(bm + srow) * Kd + ks * 32 + k0;
    if constexpr (AF32 != 0) {
      afr[0] = *(const float4v*)(Af + base);
      afr[1] = *(const float4v*)(Af + base + 4);
      afr[2] = *(const float4v*)(Af + base + 8);
      afr[3] = *(const float4v*)(Af + base + 12);
    } else {
      ah[0] = *(const short8*)(Ab + base);
      ah[1] = *(const short8*)(Ab + base + 8);
    }
  };
  auto loadB = [&](int ks) {
    size_t base = (size_t)(bn + srow) * Kd + ks * 32 + k0;
    bfr[0] = *(const float4v*)(Bp + base);
    bfr[1] = *(const float4v*)(Bp + base + 4);
    bfr[2] = *(const float4v*)(Bp + base + 8);
    bfr[3] = *(const float4v*)(Bp + base + 12);
  };
  auto packAB = [&]() {
    if constexpr (AF32 != 0) {
      ah[0] = pack8(afr[0], afr[1]);
      ah[1] = pack8(afr[2], afr[3]);
    }
    bh[0] = pack8(bfr[0], bfr[1]);
    bh[1] = pack8(bfr[2], bfr[3]);
  };
  auto writeLDS = [&](int b) {
    *(short8*)(As[b] + srow * 40 + k0)     = ah[0];
    *(short8*)(As[b] + srow * 40 + k0 + 8) = ah[1];
    *(short8*)(Bs[b] + srow * 40 + k0)     = bh[0];
    *(short8*)(Bs[b] + srow * 40 + k0 + 8) = bh[1];
  };

  // prologue: stage K-step 0 into buffer 0
  loadA(0);
  loadB(0);
  packAB();
  writeLDS(0);
  __syncthreads();

  for (int ks = 0; ks < NK; ++ks) {
    if (ks + 1 < NK) { loadA(ks + 1); loadB(ks + 1); }  // prefetch (reg)

    const int b = ks & 1;
    short8 a8[4], b8[4];
#pragma unroll
    for (int mt = 0; mt < 4; ++mt)
      a8[mt] = *(const short8*)(As[b] + (wm + mt * 16 + rl) * 40 + 8 * g);
#pragma unroll
    for (int nt = 0; nt < 4; ++nt)
      b8[nt] = *(const short8*)(Bs[b] + (wn + nt * 16 + rl) * 40 + 8 * g);
#pragma unroll
    for (int mt = 0; mt < 4; ++mt)
#pragma unroll
      for (int nt = 0; nt < 4; ++nt)
        acc[mt][nt] = __builtin_amdgcn_mfma_f32_16x16x32_bf16(a8[mt], b8[nt], acc[mt][nt], 0, 0, 0);

    if (ks + 1 < NK) {
      packAB();           // waits on prefetch loads (~1 K-step of latency budget)
      writeLDS(b ^ 1);    // other buffer: no WAR with this iteration's readers
    }
    __syncthreads();      // single barrier: buf^1 writes visible for next iter
  }

#pragma unroll
  for (int mt = 0; mt < 4; ++mt)
#pragma unroll
    for (int nt = 0; nt < 4; ++nt) {
      const int col = bn + wn + nt * 16 + rl;
      const int row0 = bm + wm + mt * 16 + 4 * g;
      if constexpr (CMODE == 1) {
        float* C = (float*)Cp;
#pragma unroll
        for (int r = 0; r < 4; ++r)
          C[(size_t)(row0 + r) * Nc + col] = acc[mt][nt][r];
      } else if constexpr (CMODE == 0) {
        unsigned short* C = (unsigned short*)Cp;
#pragma unroll
        for (int r = 0; r < 4; ++r)
          C[(size_t)(row0 + r) * Nc + col] = f2bf(acc[mt][nt][r] * oscale);
      } else {  // CMODE==2: transposed bf16: CT[col][row], lane's 4 rows contiguous
        unsigned short* C = (unsigned short*)Cp;
        short4v w = pack4(acc[mt][nt][0], acc[mt][nt][1], acc[mt][nt][2], acc[mt][nt][3]);
        *(short4v*)(C + (size_t)col * M + row0) = w;
      }
    }
}

// Fused attention, softmax over the batch axis n (size 4).  [r10 structure — best]
// Grid: (L/128, H) = (16,16) -> 1 block/CU. 512 threads = 8 waves; wave w owns
// 16 l-rows (l0 = bx*128 + w*16), all 4 n.
// qb: bf16 [n*2048+l][1024], PRE-SCALED by log2(e)/8. kb: bf16 [n*2048+s][1024].
// vtb: bf16 TRANSPOSED [h*64+dk][n*2048+s]. heads out hb: bf16 [n*2048+l][1024];
// may alias qb (block-exclusive rows x cols, read-then-write).
// LDS: FOUR 32KB buffers (counted-vmcnt pipeline, 3 stages in flight):
//   K: 4n x [32 s][128B], 16B chunk c holds global chunk c^(s&7).
//   V^T: 4n x [64 dk][64B], 16B chunk c holds global chunk c^((dk>>1)&3).
// Per iteration: compute buf t; issue stage t+3; s_waitcnt vmcnt(8); s_barrier.
__global__ __launch_bounds__(512, 2)
void attn_bn(const unsigned short* __restrict__ qb,
             const unsigned short* __restrict__ kb,
             const unsigned short* __restrict__ vtb,
             unsigned short* __restrict__ hb)
{
  __shared__ alignas(128) char smem[131072];

  const int tid = threadIdx.x;
  const int lane = tid & 63;
  const int wid = tid >> 6;          // 0..7
  const int rl = lane & 15;
  const int g = lane >> 4;
  const int h = blockIdx.y;
  const int l0 = blockIdx.x * 128 + wid * 16;

  // hoisted q B-fragments: qf[n][dh], lane holds q[l0+rl][h*64 + dh*32 + 8g + i]
  short8 qf[4][2];
#pragma unroll
  for (int n = 0; n < 4; ++n)
#pragma unroll
    for (int dh = 0; dh < 2; ++dh)
      qf[n][dh] = *(const short8*)(qb + (size_t)(n * 2048 + l0 + rl) * 1024 + h * 64 + dh * 32 + 8 * g);

  float4v ha[4][4];  // heads^T acc: ha[n][t] = dk rows 16t..16t+15, cols l
#pragma unroll
  for (int n = 0; n < 4; ++n)
#pragma unroll
    for (int t = 0; t < 4; ++t) ha[n][t] = (float4v)(0.0f);

  // staging: waves 0-3 stage K (n=wid), waves 4-7 stage V^T (n=wid-4). 4 gload16 each.
  // K swizzled: lane i -> row s=ii*8+(i>>3), global 16B chunk (i&7)^(i>>3).
  const size_t koff0 = ((size_t)(wid * 2048) + (size_t)(lane >> 3)) * 1024
                     + (size_t)(h * 64) + (size_t)(((lane & 7) ^ (lane >> 3)) * 8);
  // V^T swizzled: lane i -> row dk=ii*16+(i>>2), global 16B chunk (i&3)^((i>>3)&3).
  const size_t voff0 = ((size_t)(h * 64) + (size_t)(lane >> 2)) * 8192
                     + (size_t)((wid - 4) * 2048)
                     + (size_t)((((lane & 3) ^ ((lane >> 3) & 3)) * 8));

  auto stage = [&](int step, int b) {
    if (wid < 4) {
      char* kdst = smem + b * 32768 + wid * 4096;
      const unsigned short* ksrc = kb + koff0 + (size_t)step * 32 * 1024;
#pragma unroll
      for (int ii = 0; ii < 4; ++ii)
        gload16(ksrc + ii * 8192, kdst + ii * 1024);
    } else {
      char* vdst = smem + b * 32768 + 16384 + (wid - 4) * 4096;
      const unsigned short* vsrc = vtb + voff0 + (size_t)step * 32;
#pragma unroll
      for (int ii = 0; ii < 4; ++ii)
        gload16(vsrc + (size_t)ii * 16 * 8192, vdst + ii * 1024);
    }
  };

  // prologue: 3 stages in flight; wait until stage 0 landed (8 newer outstanding).
  stage(0, 0);
  stage(1, 1);
  stage(2, 2);
  asm volatile("s_waitcnt vmcnt(8)" ::: "memory");
  __builtin_amdgcn_s_barrier();

  const unsigned xr = ((unsigned)((rl >> 1) & 3)) << 4;
  const unsigned half = ((unsigned)(g & 1)) << 3;

  for (int to = 0; to < 16; ++to) {
#pragma unroll
    for (int ti = 0; ti < 4; ++ti) {
      const int t = to * 4 + ti;
      char* kbase = smem + ti * 32768;   // compile-time buffer base
      char* vbase = kbase + 16384;

      // scores^T = mfma(k, q): C[s][l], lane: s = ss*16 + 4g + r, l = l0 + rl.
      float4v sc[4][2];
#pragma unroll
      for (int n = 0; n < 4; ++n) {
        char* kn = kbase + n * 4096;
#pragma unroll
        for (int ss = 0; ss < 2; ++ss) {
          const int srw = ss * 16 + rl;
          const unsigned sw = ((unsigned)(srw & 7)) << 4;
          short8 kf0 = *(const short8*)(kn + srw * 128 + ((16u * (unsigned)g) ^ sw));
          short8 kf1 = *(const short8*)(kn + srw * 128 + ((64u + 16u * (unsigned)g) ^ sw));
          float4v c = (float4v)(0.0f);
          c = __builtin_amdgcn_mfma_f32_16x16x32_bf16(kf0, qf[n][0], c, 0, 0, 0);
          c = __builtin_amdgcn_mfma_f32_16x16x32_bf16(kf1, qf[n][1], c, 0, 0, 0);
          sc[n][ss] = c;
        }
      }

      // softmax over n=4. exp2 trans-op builtin; fmin bounds e <= 1.7e7, eps in
      // the sum bounds inv -> P in [0,1] always, NaN structurally impossible.
#pragma unroll
      for (int ss = 0; ss < 2; ++ss) {
        float ex[4][4];  // [n][r]
#pragma unroll
        for (int n = 0; n < 4; ++n)
#pragma unroll
          for (int r = 0; r < 4; ++r)
            ex[n][r] = EXP2(fminf(sc[n][ss][r], 24.0f));
#pragma unroll
        for (int r = 0; r < 4; ++r) {
          float inv = __builtin_amdgcn_rcpf((ex[0][r] + ex[1][r]) + (ex[2][r] + ex[3][r]) + 1e-30f);
          ex[0][r] *= inv; ex[1][r] *= inv; ex[2][r] *= inv; ex[3][r] *= inv;
        }
        short4v pf[4];
#pragma unroll
        for (int n = 0; n < 4; ++n)
          pf[n] = pack4(ex[n][0], ex[n][1], ex[n][2], ex[n][3]);

        // PV half: heads^T[dk][l] += V^T[:, 16ss..16ss+16) * P^T half (16x16x16).
        // A slot (g,i) <- V^T[dk=16t4+rl][s=16ss+4g+i]; 8B block b=4ss+g of row dk
        // lives at chunk (b>>1)^((dk>>1)&3), half b&1.
        const unsigned chunk0 = 2u * (unsigned)ss + ((unsigned)g >> 1);
#pragma unroll
        for (int n = 0; n < 4; ++n) {
          char* vn = vbase + n * 4096;
#pragma unroll
          for (int t4 = 0; t4 < 4; ++t4) {
            const char* rowp = vn + (t4 * 16 + rl) * 64;
            short4v va = *(const short4v*)(rowp + (((chunk0 << 4) ^ xr) + half));
            ha[n][t4] = __builtin_amdgcn_mfma_f32_16x16x16bf16_1k(va, pf[n], ha[n][t4], 0, 0, 0);
          }
        }
      }

      if (t + 3 < 64) stage(t + 3, (ti + 3) & 3);
      asm volatile("s_waitcnt vmcnt(8)" ::: "memory");
      __builtin_amdgcn_s_barrier();
    }
  }

  // epilogue: heads^T C-frag -> heads[n*2048+l][h*64+dk] bf16, 8B stores
#pragma unroll
  for (int n = 0; n < 4; ++n)
#pragma unroll
    for (int tt = 0; tt < 4; ++tt) {
      short4v w = pack4(ha[n][tt][0], ha[n][tt][1], ha[n][tt][2], ha[n][tt][3]);
      size_t off = (size_t)(n * 2048 + l0 + rl) * 1024 + h * 64 + tt * 16 + 4 * g;
      *(short4v*)(hb + off) = w;
    }
}

extern "C" void kernel_launch(void* const* d_in, const int* in_sizes, int n_in,
                              void* d_out, int out_size, void* d_ws, size_t ws_size,
                              hipStream_t stream)
{
  const float* Q  = (const float*)d_in[0];
  const float* K  = (const float*)d_in[1];
  const float* V  = (const float*)d_in[2];
  const float* Wq = (const float*)d_in[3];
  const float* Wo = (const float*)d_in[4];

  unsigned short* qb = (unsigned short*)d_ws;            // 16 MB each
  unsigned short* kw = qb + (size_t)8192 * 1024;
  unsigned short* vt = kw + (size_t)8192 * 1024;         // v^T [1024][8192]
  unsigned short* hw = qb;  // heads alias q (block-exclusive read-then-write)

  const float CS = 0.18033688011112042f;  // log2(e)/8: folds 1/sqrt(dk) + ln2 into q

  dim3 gg(64, 8), bb(256);
  gemm_bt128<1, 0><<<gg, bb, 0, stream>>>(Q, Wq, qb, 8192, 1024, 1024, CS);
  gemm_bt128<1, 0><<<gg, bb, 0, stream>>>(K, Wq, kw, 8192, 1024, 1024, 1.0f);
  gemm_bt128<1, 2><<<gg, bb, 0, stream>>>(V, Wq, vt, 8192, 1024, 1024, 1.0f);
  attn_bn<<<dim3(16, 16), dim3(512), 0, stream>>>(qb, kw, vt, hw);
  gemm_bt128<0, 1><<<gg, bb, 0, stream>>>(hw, Wo, (float*)d_out, 8192, 1024, 1024, 1.0f);
}